// Round 1
// baseline (1020.069 us; speedup 1.0000x reference)
//
#include <hip/hip_runtime.h>

#define N_NODES 100000
#define N_EDGES 1200000
#define D 64
#define N_CLASSES 16

// --- Edge scatter-add: agg[dst[e]][c] += h[src[e]][c] ---------------------
// One wave (64 lanes) per edge; lane = feature channel. Gather of the source
// row is a fully-coalesced 256B read; scatter is 64 f32 atomics.
__global__ void edge_agg_kernel(const float* __restrict__ h,
                                const int* __restrict__ src,
                                const int* __restrict__ dst,
                                float* __restrict__ agg) {
    long long t = (long long)blockIdx.x * blockDim.x + threadIdx.x;
    int e = (int)(t >> 6);
    int c = (int)(t & 63);
    if (e >= N_EDGES) return;
    int s = src[e];
    int d = dst[e];
    float v = h[(size_t)s * D + c];
    atomicAdd(&agg[(size_t)d * D + c], v);
}

// --- Node MLP: h_out[n] = relu((h_in[n] + agg[n]) @ W) --------------------
// 256 threads = 4 nodes/block (1 wave per node). W (64x64, [in][out]) staged
// in LDS; per-node input row staged in LDS; each lane computes one output.
// Safe for h_in == h_out (each element read exactly once before any write).
__global__ void node_mlp_kernel(const float* __restrict__ h_in,
                                const float* __restrict__ agg,
                                const float* __restrict__ W,
                                float* __restrict__ h_out) {
    __shared__ float Ws[D][D];   // Ws[i][o]
    __shared__ float vs[4][D];
    int tid = threadIdx.x;
    for (int k = tid; k < D * D; k += 256)
        Ws[k / D][k % D] = W[k];
    int w = tid >> 6;
    int lane = tid & 63;
    int n = blockIdx.x * 4 + w;
    float v = 0.f;
    if (n < N_NODES)
        v = h_in[(size_t)n * D + lane] + agg[(size_t)n * D + lane];
    vs[w][lane] = v;
    __syncthreads();
    if (n < N_NODES) {
        float acc = 0.f;
#pragma unroll
        for (int i = 0; i < D; ++i)
            acc = fmaf(vs[w][i], Ws[i][lane], acc);
        h_out[(size_t)n * D + lane] = fmaxf(acc, 0.f);
    }
}

// --- Final: L2-normalize rows of h, write feat; out = feat @ W_out + b ----
// Safe for h == feat (in-place normalize).
__global__ void final_kernel(const float* __restrict__ h,
                             const float* __restrict__ W_out,
                             const float* __restrict__ b_out,
                             float* __restrict__ out,    // [N, 16]
                             float* __restrict__ feat) { // [N, 64]
    __shared__ float Ws[D][N_CLASSES]; // 64 x 16
    __shared__ float fs[4][D];
    int tid = threadIdx.x;
    for (int k = tid; k < D * N_CLASSES; k += 256)
        Ws[k / N_CLASSES][k % N_CLASSES] = W_out[k];
    int w = tid >> 6;
    int lane = tid & 63;
    int n = blockIdx.x * 4 + w;
    float v = 0.f;
    if (n < N_NODES) v = h[(size_t)n * D + lane];
    float ss = v * v;
#pragma unroll
    for (int off = 32; off; off >>= 1)
        ss += __shfl_xor(ss, off);
    float nrm = sqrtf(ss);
    float f = v / fmaxf(nrm, 1e-12f);
    if (n < N_NODES) feat[(size_t)n * D + lane] = f;
    fs[w][lane] = f;
    __syncthreads();
    if (n < N_NODES && lane < N_CLASSES) {
        float acc = b_out[lane];
#pragma unroll
        for (int i = 0; i < D; ++i)
            acc = fmaf(fs[w][i], Ws[i][lane], acc);
        out[(size_t)n * N_CLASSES + lane] = acc;
    }
}

extern "C" void kernel_launch(void* const* d_in, const int* in_sizes, int n_in,
                              void* d_out, int out_size, void* d_ws, size_t ws_size,
                              hipStream_t stream) {
    const float* x     = (const float*)d_in[0];
    const int*   src   = (const int*)d_in[1];
    const int*   dst   = (const int*)d_in[2];
    const float* W0    = (const float*)d_in[3];
    const float* W1    = (const float*)d_in[4];
    const float* W2    = (const float*)d_in[5];
    const float* W_out = (const float*)d_in[6];
    const float* b_out = (const float*)d_in[7];

    float* out  = (float*)d_out;                       // [N, 16]
    float* hbuf = (float*)d_out + (size_t)N_NODES * N_CLASSES; // feat region, doubles as h
    float* agg  = (float*)d_ws;                        // 25.6 MB scratch

    const size_t agg_bytes = (size_t)N_NODES * D * sizeof(float);
    const int edge_blocks = (N_EDGES * 64) / 256;      // 300000 exactly
    const int node_blocks = (N_NODES + 3) / 4;         // 25000 exactly

    const float* Ws[3] = {W0, W1, W2};
    const float* h_in = x;
    for (int layer = 0; layer < 3; ++layer) {
        hipMemsetAsync(agg, 0, agg_bytes, stream);
        edge_agg_kernel<<<edge_blocks, 256, 0, stream>>>(h_in, src, dst, agg);
        node_mlp_kernel<<<node_blocks, 256, 0, stream>>>(h_in, agg, Ws[layer], hbuf);
        h_in = hbuf; // layers 2,3 run in-place on the feat region
    }

    final_kernel<<<node_blocks, 256, 0, stream>>>(hbuf, W_out, b_out, out, hbuf);
}

// Round 2
// 466.234 us; speedup vs baseline: 2.1879x; 2.1879x over previous
//
#include <hip/hip_runtime.h>

#define N_NODES 100000
#define N_EDGES 1200000
#define D 64
#define N_CLASSES 16

// ======================= CSR build kernels ================================

__global__ void hist_kernel(const int* __restrict__ dst, int* __restrict__ cnt) {
    int e = blockIdx.x * 256 + threadIdx.x;
    if (e < N_EDGES) atomicAdd(&cnt[dst[e]], 1);
}

// Per-block local exclusive scan of 256-chunks; block totals to partial[].
__global__ void scan_block_kernel(const int* __restrict__ cnt,
                                  int* __restrict__ ofs,
                                  int* __restrict__ partial) {
    __shared__ int s[256];
    int tid = threadIdx.x;
    int i = blockIdx.x * 256 + tid;
    int v = (i < N_NODES) ? cnt[i] : 0;
    s[tid] = v;
    __syncthreads();
    for (int d = 1; d < 256; d <<= 1) {
        int t = (tid >= d) ? s[tid - d] : 0;
        __syncthreads();
        s[tid] += t;
        __syncthreads();
    }
    if (i < N_NODES) ofs[i] = s[tid] - v;       // local exclusive
    if (tid == 255) partial[blockIdx.x] = s[255]; // block total
}

__global__ void scan_partials_kernel(int* __restrict__ partial, int nb) {
    __shared__ int s[512];
    int tid = threadIdx.x;
    int v = (tid < nb) ? partial[tid] : 0;
    s[tid] = v;
    __syncthreads();
    for (int d = 1; d < 512; d <<= 1) {
        int t = (tid >= d) ? s[tid - d] : 0;
        __syncthreads();
        s[tid] += t;
        __syncthreads();
    }
    if (tid < nb) partial[tid] = s[tid] - v;    // exclusive
}

__global__ void scan_add_kernel(int* __restrict__ ofs, const int* __restrict__ partial) {
    int i = blockIdx.x * 256 + threadIdx.x;
    if (i < N_NODES) ofs[i] += partial[blockIdx.x];
    if (i == 0) ofs[N_NODES] = N_EDGES;
}

__global__ void scatter_edges_kernel(const int* __restrict__ src,
                                     const int* __restrict__ dst,
                                     const int* __restrict__ ofs,
                                     int* __restrict__ cursor,
                                     int* __restrict__ esrc) {
    int e = blockIdx.x * 256 + threadIdx.x;
    if (e >= N_EDGES) return;
    int d = dst[e];
    int p = ofs[d] + atomicAdd(&cursor[d], 1);
    esrc[p] = src[e];
}

// ============ Fused GIN layer: gather-sum + MLP + relu ====================
// 256 threads = 4 nodes (1 wave per node), lane = feature channel.
// acc = h[n] + sum_{k in in-edges(n)} h[esrc[k]]; out = relu(acc @ W).
__global__ void gin_layer_kernel(const float* __restrict__ h_in,
                                 const int* __restrict__ ofs,
                                 const int* __restrict__ esrc,
                                 const float* __restrict__ W,
                                 float* __restrict__ h_out) {
    __shared__ float Ws[D][D];   // [in][out]
    __shared__ float vs[4][D];
    int tid = threadIdx.x;
    for (int k = tid; k < D * D; k += 256)
        Ws[k / D][k % D] = W[k];
    int w = tid >> 6, lane = tid & 63;
    int n = blockIdx.x * 4 + w;
    float acc = 0.f;
    if (n < N_NODES) {
        acc = h_in[(size_t)n * D + lane];
        int beg = ofs[n], end = ofs[n + 1];
        int k = beg;
        for (; k + 4 <= end; k += 4) {   // 4x unroll for load ILP
            int s0 = esrc[k], s1 = esrc[k + 1], s2 = esrc[k + 2], s3 = esrc[k + 3];
            float v0 = h_in[(size_t)s0 * D + lane];
            float v1 = h_in[(size_t)s1 * D + lane];
            float v2 = h_in[(size_t)s2 * D + lane];
            float v3 = h_in[(size_t)s3 * D + lane];
            acc += v0; acc += v1; acc += v2; acc += v3;
        }
        for (; k < end; ++k)
            acc += h_in[(size_t)esrc[k] * D + lane];
    }
    vs[w][lane] = acc;
    __syncthreads();
    if (n < N_NODES) {
        float o = 0.f;
#pragma unroll
        for (int i = 0; i < D; ++i)
            o = fmaf(vs[w][i], Ws[i][lane], o);
        h_out[(size_t)n * D + lane] = fmaxf(o, 0.f);
    }
}

// ============ Final: L2-normalize + 64->16 linear =========================
__global__ void final_kernel(const float* __restrict__ h,
                             const float* __restrict__ W_out,
                             const float* __restrict__ b_out,
                             float* __restrict__ out,    // [N, 16]
                             float* __restrict__ feat) { // [N, 64]
    __shared__ float Ws[D][N_CLASSES];
    __shared__ float fs[4][D];
    int tid = threadIdx.x;
    for (int k = tid; k < D * N_CLASSES; k += 256)
        Ws[k / N_CLASSES][k % N_CLASSES] = W_out[k];
    int w = tid >> 6, lane = tid & 63;
    int n = blockIdx.x * 4 + w;
    float v = 0.f;
    if (n < N_NODES) v = h[(size_t)n * D + lane];
    float ss = v * v;
#pragma unroll
    for (int off = 32; off; off >>= 1)
        ss += __shfl_xor(ss, off);
    float f = v / fmaxf(sqrtf(ss), 1e-12f);
    if (n < N_NODES) feat[(size_t)n * D + lane] = f;
    fs[w][lane] = f;
    __syncthreads();
    if (n < N_NODES && lane < N_CLASSES) {
        float acc = b_out[lane];
#pragma unroll
        for (int i = 0; i < D; ++i)
            acc = fmaf(fs[w][i], Ws[i][lane], acc);
        out[(size_t)n * N_CLASSES + lane] = acc;
    }
}

// ================= Fallback (round-1 atomic path) =========================
__global__ void edge_agg_kernel(const float* __restrict__ h,
                                const int* __restrict__ src,
                                const int* __restrict__ dst,
                                float* __restrict__ agg) {
    long long t = (long long)blockIdx.x * blockDim.x + threadIdx.x;
    int e = (int)(t >> 6);
    int c = (int)(t & 63);
    if (e >= N_EDGES) return;
    atomicAdd(&agg[(size_t)dst[e] * D + c], h[(size_t)src[e] * D + c]);
}

__global__ void node_mlp_kernel(const float* __restrict__ h_in,
                                const float* __restrict__ agg,
                                const float* __restrict__ W,
                                float* __restrict__ h_out) {
    __shared__ float Ws[D][D];
    __shared__ float vs[4][D];
    int tid = threadIdx.x;
    for (int k = tid; k < D * D; k += 256)
        Ws[k / D][k % D] = W[k];
    int w = tid >> 6, lane = tid & 63;
    int n = blockIdx.x * 4 + w;
    float v = 0.f;
    if (n < N_NODES)
        v = h_in[(size_t)n * D + lane] + agg[(size_t)n * D + lane];
    vs[w][lane] = v;
    __syncthreads();
    if (n < N_NODES) {
        float acc = 0.f;
#pragma unroll
        for (int i = 0; i < D; ++i)
            acc = fmaf(vs[w][i], Ws[i][lane], acc);
        h_out[(size_t)n * D + lane] = fmaxf(acc, 0.f);
    }
}

// ==========================================================================
extern "C" void kernel_launch(void* const* d_in, const int* in_sizes, int n_in,
                              void* d_out, int out_size, void* d_ws, size_t ws_size,
                              hipStream_t stream) {
    const float* x     = (const float*)d_in[0];
    const int*   src   = (const int*)d_in[1];
    const int*   dst   = (const int*)d_in[2];
    const float* W0    = (const float*)d_in[3];
    const float* W1    = (const float*)d_in[4];
    const float* W2    = (const float*)d_in[5];
    const float* W_out = (const float*)d_in[6];
    const float* b_out = (const float*)d_in[7];

    float* out  = (float*)d_out;                                  // [N,16]
    float* hbuf = (float*)d_out + (size_t)N_NODES * N_CLASSES;    // feat region [N,64]

    const int NB_NODE = (N_NODES + 255) / 256;  // 391
    const int NB_EDGE = (N_EDGES + 255) / 256;  // 4688
    const int node_blocks = (N_NODES + 3) / 4;  // 25000

    // ws layout (256B-aligned slabs)
    size_t off = 0;
    auto alloc = [&](size_t bytes) { size_t o = off; off = (off + bytes + 255) & ~(size_t)255; return o; };
    size_t o_cnt     = alloc((size_t)N_NODES * 4);
    size_t o_partial = alloc(512 * 4);
    size_t o_ofs     = alloc(((size_t)N_NODES + 1) * 4);
    size_t o_esrc    = alloc((size_t)N_EDGES * 4);
    size_t o_bufA    = alloc((size_t)N_NODES * D * 4);
    size_t need = off;

    char* w8 = (char*)d_ws;

    if (ws_size >= need) {
        int*   cnt     = (int*)(w8 + o_cnt);
        int*   partial = (int*)(w8 + o_partial);
        int*   ofs     = (int*)(w8 + o_ofs);
        int*   esrc    = (int*)(w8 + o_esrc);
        float* bufA    = (float*)(w8 + o_bufA);

        // --- CSR build (once, reused by 3 layers) ---
        hipMemsetAsync(cnt, 0, (size_t)N_NODES * 4, stream);
        hist_kernel<<<NB_EDGE, 256, 0, stream>>>(dst, cnt);
        scan_block_kernel<<<NB_NODE, 256, 0, stream>>>(cnt, ofs, partial);
        scan_partials_kernel<<<1, 512, 0, stream>>>(partial, NB_NODE);
        scan_add_kernel<<<NB_NODE, 256, 0, stream>>>(ofs, partial);
        hipMemsetAsync(cnt, 0, (size_t)N_NODES * 4, stream);  // reuse as cursor
        scatter_edges_kernel<<<NB_EDGE, 256, 0, stream>>>(src, dst, ofs, cnt, esrc);

        // --- 3 fused GIN layers (ping-pong bufA <-> hbuf) ---
        gin_layer_kernel<<<node_blocks, 256, 0, stream>>>(x,    ofs, esrc, W0, bufA);
        gin_layer_kernel<<<node_blocks, 256, 0, stream>>>(bufA, ofs, esrc, W1, hbuf);
        gin_layer_kernel<<<node_blocks, 256, 0, stream>>>(hbuf, ofs, esrc, W2, bufA);

        final_kernel<<<node_blocks, 256, 0, stream>>>(bufA, W_out, b_out, out, hbuf);
    } else {
        // Fallback: round-1 atomic path (needs only 25.6MB)
        float* agg = (float*)d_ws;
        const size_t agg_bytes = (size_t)N_NODES * D * 4;
        const int edge_blocks = (N_EDGES * 64) / 256;
        const float* Wl[3] = {W0, W1, W2};
        const float* h_in = x;
        for (int layer = 0; layer < 3; ++layer) {
            hipMemsetAsync(agg, 0, agg_bytes, stream);
            edge_agg_kernel<<<edge_blocks, 256, 0, stream>>>(h_in, src, dst, agg);
            node_mlp_kernel<<<node_blocks, 256, 0, stream>>>(h_in, agg, Wl[layer], hbuf);
            h_in = hbuf;
        }
        final_kernel<<<node_blocks, 256, 0, stream>>>(hbuf, W_out, b_out, out, hbuf);
    }
}

// Round 3
// 392.005 us; speedup vs baseline: 2.6022x; 1.1894x over previous
//
#include <hip/hip_runtime.h>

#define N_NODES 100000
#define N_EDGES 1200000
#define D 64
#define N_CLASSES 16
#define NGROUPS (N_NODES / 4)      // 25000 groups of 4 nodes (N divisible by 4)
#define GIN_GRID 2048              // 8 blocks/CU (LDS-limited at 17.4KB)

// ======================= CSR build kernels ================================

__global__ void hist_kernel(const int* __restrict__ dst, int* __restrict__ cnt) {
    int e = (blockIdx.x * 256 + threadIdx.x) * 4;
    if (e + 4 <= N_EDGES) {
        int4 d4 = *(const int4*)(dst + e);
        atomicAdd(&cnt[d4.x], 1); atomicAdd(&cnt[d4.y], 1);
        atomicAdd(&cnt[d4.z], 1); atomicAdd(&cnt[d4.w], 1);
    } else {
        for (int k = e; k < N_EDGES; ++k) atomicAdd(&cnt[dst[k]], 1);
    }
}

__global__ void scan_block_kernel(const int* __restrict__ cnt,
                                  int* __restrict__ ofs,
                                  int* __restrict__ partial) {
    __shared__ int s[256];
    int tid = threadIdx.x;
    int i = blockIdx.x * 256 + tid;
    int v = (i < N_NODES) ? cnt[i] : 0;
    s[tid] = v;
    __syncthreads();
    for (int d = 1; d < 256; d <<= 1) {
        int t = (tid >= d) ? s[tid - d] : 0;
        __syncthreads();
        s[tid] += t;
        __syncthreads();
    }
    if (i < N_NODES) ofs[i] = s[tid] - v;
    if (tid == 255) partial[blockIdx.x] = s[255];
}

__global__ void scan_partials_kernel(int* __restrict__ partial, int nb) {
    __shared__ int s[512];
    int tid = threadIdx.x;
    int v = (tid < nb) ? partial[tid] : 0;
    s[tid] = v;
    __syncthreads();
    for (int d = 1; d < 512; d <<= 1) {
        int t = (tid >= d) ? s[tid - d] : 0;
        __syncthreads();
        s[tid] += t;
        __syncthreads();
    }
    if (tid < nb) partial[tid] = s[tid] - v;
}

__global__ void scan_add_kernel(int* __restrict__ ofs, const int* __restrict__ partial) {
    int i = blockIdx.x * 256 + threadIdx.x;
    if (i < N_NODES) ofs[i] += partial[blockIdx.x];
    if (i == 0) ofs[N_NODES] = N_EDGES;
}

// Uses cnt (post-histogram counts) as a down-cursor: no second memset needed.
__global__ void scatter_edges_kernel(const int* __restrict__ src,
                                     const int* __restrict__ dst,
                                     const int* __restrict__ ofs,
                                     int* __restrict__ cnt,
                                     int* __restrict__ esrc) {
    int e = (blockIdx.x * 256 + threadIdx.x) * 4;
    if (e + 4 <= N_EDGES) {
        int4 s4 = *(const int4*)(src + e);
        int4 d4 = *(const int4*)(dst + e);
        esrc[ofs[d4.x] + atomicSub(&cnt[d4.x], 1) - 1] = s4.x;
        esrc[ofs[d4.y] + atomicSub(&cnt[d4.y], 1) - 1] = s4.y;
        esrc[ofs[d4.z] + atomicSub(&cnt[d4.z], 1) - 1] = s4.z;
        esrc[ofs[d4.w] + atomicSub(&cnt[d4.w], 1) - 1] = s4.w;
    } else {
        for (int k = e; k < N_EDGES; ++k)
            esrc[ofs[dst[k]] + atomicSub(&cnt[dst[k]], 1) - 1] = src[k];
    }
}

// ============ Fused GIN layer: gather-sum + MLP + relu ====================
// Grid-stride persistent blocks: Ws staged ONCE per block (not per group).
// 4 waves/block, 1 node per wave; waves fully decoupled after the one
// staging barrier (vs[] staging is wave-local -> no __syncthreads needed:
// the compiler orders same-wave LDS RAW via lgkmcnt).
__global__ __launch_bounds__(256) void gin_layer_kernel(
        const float* __restrict__ h_in,
        const int* __restrict__ ofs,
        const int* __restrict__ esrc,
        const float* __restrict__ W,
        float* __restrict__ h_out) {
    __shared__ float Ws[D][D];   // [in][out], 16KB
    __shared__ float vs[4][D];
    int tid = threadIdx.x;
    for (int k = tid; k < D * D; k += 256)
        Ws[k >> 6][k & 63] = W[k];
    __syncthreads();   // the only barrier
    int w = tid >> 6, lane = tid & 63;

    for (int g = blockIdx.x; g < NGROUPS; g += GIN_GRID) {
        int n = g * 4 + w;
        // 8 independent accumulators -> 8 gathers in flight
        float a0 = h_in[(size_t)n * D + lane];  // self term
        float a1 = 0.f, a2 = 0.f, a3 = 0.f, a4 = 0.f, a5 = 0.f, a6 = 0.f, a7 = 0.f;
        int k = ofs[n], end = ofs[n + 1];
        for (; k + 8 <= end; k += 8) {
            int s0 = esrc[k + 0], s1 = esrc[k + 1], s2 = esrc[k + 2], s3 = esrc[k + 3];
            int s4 = esrc[k + 4], s5 = esrc[k + 5], s6 = esrc[k + 6], s7 = esrc[k + 7];
            a0 += h_in[(size_t)s0 * D + lane]; a1 += h_in[(size_t)s1 * D + lane];
            a2 += h_in[(size_t)s2 * D + lane]; a3 += h_in[(size_t)s3 * D + lane];
            a4 += h_in[(size_t)s4 * D + lane]; a5 += h_in[(size_t)s5 * D + lane];
            a6 += h_in[(size_t)s6 * D + lane]; a7 += h_in[(size_t)s7 * D + lane];
        }
        if (k + 4 <= end) {
            int s0 = esrc[k + 0], s1 = esrc[k + 1], s2 = esrc[k + 2], s3 = esrc[k + 3];
            a1 += h_in[(size_t)s0 * D + lane]; a2 += h_in[(size_t)s1 * D + lane];
            a3 += h_in[(size_t)s2 * D + lane]; a4 += h_in[(size_t)s3 * D + lane];
            k += 4;
        }
        if (k + 2 <= end) {
            int s0 = esrc[k + 0], s1 = esrc[k + 1];
            a5 += h_in[(size_t)s0 * D + lane]; a6 += h_in[(size_t)s1 * D + lane];
            k += 2;
        }
        if (k < end)
            a7 += h_in[(size_t)esrc[k] * D + lane];

        vs[w][lane] = ((a0 + a1) + (a2 + a3)) + ((a4 + a5) + (a6 + a7));
        // wave-local LDS RAW: no barrier
        float o = 0.f;
#pragma unroll
        for (int i = 0; i < D; ++i)
            o = fmaf(vs[w][i], Ws[i][lane], o);
        h_out[(size_t)n * D + lane] = fmaxf(o, 0.f);
    }
}

// ============ Final: L2-normalize + 64->16 linear =========================
__global__ __launch_bounds__(256) void final_kernel(
        const float* __restrict__ h,
        const float* __restrict__ W_out,
        const float* __restrict__ b_out,
        float* __restrict__ out,    // [N, 16]
        float* __restrict__ feat) { // [N, 64]
    __shared__ float Ws[D][N_CLASSES];
    __shared__ float fs[4][D];
    int tid = threadIdx.x;
    for (int k = tid; k < D * N_CLASSES; k += 256)
        Ws[k / N_CLASSES][k % N_CLASSES] = W_out[k];
    __syncthreads();
    int w = tid >> 6, lane = tid & 63;
    float bias = b_out[lane & 15];

    for (int g = blockIdx.x; g < NGROUPS; g += GIN_GRID) {
        int n = g * 4 + w;
        float v = h[(size_t)n * D + lane];
        float ss = v * v;
#pragma unroll
        for (int off = 32; off; off >>= 1)
            ss += __shfl_xor(ss, off);
        float f = v / fmaxf(sqrtf(ss), 1e-12f);
        feat[(size_t)n * D + lane] = f;
        fs[w][lane] = f;
        // wave-local LDS RAW: no barrier
        if (lane < N_CLASSES) {
            float acc = bias;
#pragma unroll
            for (int i = 0; i < D; ++i)
                acc = fmaf(fs[w][i], Ws[i][lane], acc);
            out[(size_t)n * N_CLASSES + lane] = acc;
        }
    }
}

// ==========================================================================
extern "C" void kernel_launch(void* const* d_in, const int* in_sizes, int n_in,
                              void* d_out, int out_size, void* d_ws, size_t ws_size,
                              hipStream_t stream) {
    const float* x     = (const float*)d_in[0];
    const int*   src   = (const int*)d_in[1];
    const int*   dst   = (const int*)d_in[2];
    const float* W0    = (const float*)d_in[3];
    const float* W1    = (const float*)d_in[4];
    const float* W2    = (const float*)d_in[5];
    const float* W_out = (const float*)d_in[6];
    const float* b_out = (const float*)d_in[7];

    float* out  = (float*)d_out;                                  // [N,16]
    float* hbuf = (float*)d_out + (size_t)N_NODES * N_CLASSES;    // feat region [N,64]

    const int NB_NODE  = (N_NODES + 255) / 256;       // 391
    const int NB_EDGE4 = (N_EDGES / 4 + 255) / 256;   // 1172

    // ws layout (256B-aligned slabs) — same as round 2
    size_t off = 0;
    auto alloc = [&](size_t bytes) { size_t o = off; off = (off + bytes + 255) & ~(size_t)255; return o; };
    size_t o_cnt     = alloc((size_t)N_NODES * 4);
    size_t o_partial = alloc(512 * 4);
    size_t o_ofs     = alloc(((size_t)N_NODES + 1) * 4);
    size_t o_esrc    = alloc((size_t)N_EDGES * 4);
    size_t o_bufA    = alloc((size_t)N_NODES * D * 4);

    char* w8 = (char*)d_ws;
    int*   cnt     = (int*)(w8 + o_cnt);
    int*   partial = (int*)(w8 + o_partial);
    int*   ofs     = (int*)(w8 + o_ofs);
    int*   esrc    = (int*)(w8 + o_esrc);
    float* bufA    = (float*)(w8 + o_bufA);

    // --- CSR build (once, reused by 3 layers) ---
    hipMemsetAsync(cnt, 0, (size_t)N_NODES * 4, stream);
    hist_kernel<<<NB_EDGE4, 256, 0, stream>>>(dst, cnt);
    scan_block_kernel<<<NB_NODE, 256, 0, stream>>>(cnt, ofs, partial);
    scan_partials_kernel<<<1, 512, 0, stream>>>(partial, NB_NODE);
    scan_add_kernel<<<NB_NODE, 256, 0, stream>>>(ofs, partial);
    scatter_edges_kernel<<<NB_EDGE4, 256, 0, stream>>>(src, dst, ofs, cnt, esrc);

    // --- 3 fused GIN layers (ping-pong bufA <-> hbuf) ---
    gin_layer_kernel<<<GIN_GRID, 256, 0, stream>>>(x,    ofs, esrc, W0, bufA);
    gin_layer_kernel<<<GIN_GRID, 256, 0, stream>>>(bufA, ofs, esrc, W1, hbuf);
    gin_layer_kernel<<<GIN_GRID, 256, 0, stream>>>(hbuf, ofs, esrc, W2, bufA);

    final_kernel<<<GIN_GRID, 256, 0, stream>>>(bufA, W_out, b_out, out, hbuf);
}

// Round 4
// 371.902 us; speedup vs baseline: 2.7428x; 1.0541x over previous
//
#include <hip/hip_runtime.h>
#include <hip/hip_fp16.h>

#define N_NODES 100000
#define N_EDGES 1200000
#define D 64
#define N_CLASSES 16
#define NGROUPS (N_NODES / 4)      // 25000 groups of 4 nodes
#define GIN_GRID 2048              // 8 blocks/CU (LDS 17.4KB -> 9 max)
#define GIN3_GRID 1792             // fused layer3 has 22.5KB LDS -> 7 blocks/CU
#define NXCD 8
#define DRANGE ((N_NODES + NXCD - 1) / NXCD)   // 12500

// ======================= CSR build kernels ================================

__global__ void hist_kernel(const int* __restrict__ dst, int* __restrict__ cnt) {
    int e = (blockIdx.x * 256 + threadIdx.x) * 4;
    if (e + 4 <= N_EDGES) {
        int4 d4 = *(const int4*)(dst + e);
        atomicAdd(&cnt[d4.x], 1); atomicAdd(&cnt[d4.y], 1);
        atomicAdd(&cnt[d4.z], 1); atomicAdd(&cnt[d4.w], 1);
    } else {
        for (int k = e; k < N_EDGES; ++k) atomicAdd(&cnt[dst[k]], 1);
    }
}

__global__ void scan_block_kernel(const int* __restrict__ cnt,
                                  int* __restrict__ ofs,
                                  int* __restrict__ partial) {
    __shared__ int s[256];
    int tid = threadIdx.x;
    int i = blockIdx.x * 256 + tid;
    int v = (i < N_NODES) ? cnt[i] : 0;
    s[tid] = v;
    __syncthreads();
    for (int d = 1; d < 256; d <<= 1) {
        int t = (tid >= d) ? s[tid - d] : 0;
        __syncthreads();
        s[tid] += t;
        __syncthreads();
    }
    if (i < N_NODES) ofs[i] = s[tid] - v;
    if (tid == 255) partial[blockIdx.x] = s[255];
}

__global__ void scan_partials_kernel(int* __restrict__ partial, int nb) {
    __shared__ int s[512];
    int tid = threadIdx.x;
    int v = (tid < nb) ? partial[tid] : 0;
    s[tid] = v;
    __syncthreads();
    for (int d = 1; d < 512; d <<= 1) {
        int t = (tid >= d) ? s[tid - d] : 0;
        __syncthreads();
        s[tid] += t;
        __syncthreads();
    }
    if (tid < nb) partial[tid] = s[tid] - v;
}

__global__ void scan_add_kernel(int* __restrict__ ofs, const int* __restrict__ partial) {
    int i = blockIdx.x * 256 + threadIdx.x;
    if (i < N_NODES) ofs[i] += partial[blockIdx.x];
    if (i == 0) ofs[N_NODES] = N_EDGES;
}

// XCD-range-partitioned scatter: block (blockIdx&7) -> XCD (round-robin
// dispatch heuristic) handles only dst in its 12500-node range, so each
// XCD's esrc slice (~600KB) stays hot in its OWN L2 -> kills the 18x
// write amplification seen in round 3. Costs 8x re-read of src/dst
// (L3-resident). cnt is the post-histogram count used as a down-cursor.
__global__ __launch_bounds__(256) void scatter_edges_kernel(
        const int* __restrict__ src,
        const int* __restrict__ dst,
        const int* __restrict__ ofs,
        int* __restrict__ cnt,
        int* __restrict__ esrc) {
    int g = blockIdx.x & (NXCD - 1);
    int lo = g * DRANGE, hi = lo + DRANGE;
    int t = (blockIdx.x >> 3) * 256 + threadIdx.x;       // 0..65535 within group
    const int NCH = N_EDGES / 4;                          // 300000
    const int STRIDE = (2048 / NXCD) * 256;               // 65536
    for (int c = t; c < NCH; c += STRIDE) {
        int4 s4 = ((const int4*)src)[c];
        int4 d4 = ((const int4*)dst)[c];
        if (d4.x >= lo && d4.x < hi) esrc[ofs[d4.x] + atomicSub(&cnt[d4.x], 1) - 1] = s4.x;
        if (d4.y >= lo && d4.y < hi) esrc[ofs[d4.y] + atomicSub(&cnt[d4.y], 1) - 1] = s4.y;
        if (d4.z >= lo && d4.z < hi) esrc[ofs[d4.z] + atomicSub(&cnt[d4.z], 1) - 1] = s4.z;
        if (d4.w >= lo && d4.w < hi) esrc[ofs[d4.w] + atomicSub(&cnt[d4.w], 1) - 1] = s4.w;
    }
}

// ================= f32 -> f16 convert (for layer-0 input) =================
__global__ void cvt_f32_f16_kernel(const float* __restrict__ in, __half* __restrict__ out) {
    const int N4 = N_NODES * D / 4;
    int i = blockIdx.x * 256 + threadIdx.x;
    if (i < N4) {
        float4 v = ((const float4*)in)[i];
        ((__half2*)out)[2 * i + 0] = __floats2half2_rn(v.x, v.y);
        ((__half2*)out)[2 * i + 1] = __floats2half2_rn(v.z, v.w);
    }
}

// ============ Fused GIN layer: gather-sum + MLP + relu (fp16 h) ===========
// Persistent grid-stride blocks; Ws staged once; 1 wave = 1 node; waves
// decoupled after the one staging barrier (vs[] is wave-local).
__global__ __launch_bounds__(256) void gin_layer_kernel(
        const __half* __restrict__ h_in,
        const int* __restrict__ ofs,
        const int* __restrict__ esrc,
        const float* __restrict__ W,
        __half* __restrict__ h_out) {
    __shared__ float Ws[D][D];   // [in][out], 16KB
    __shared__ float vs[4][D];
    int tid = threadIdx.x;
    for (int k = tid; k < D * D; k += 256)
        Ws[k >> 6][k & 63] = W[k];
    __syncthreads();   // the only barrier
    int w = tid >> 6, lane = tid & 63;

    for (int g = blockIdx.x; g < NGROUPS; g += GIN_GRID) {
        int n = g * 4 + w;
        float a0 = __half2float(h_in[(size_t)n * D + lane]);  // self term
        float a1 = 0.f, a2 = 0.f, a3 = 0.f, a4 = 0.f, a5 = 0.f, a6 = 0.f, a7 = 0.f;
        int k = ofs[n], end = ofs[n + 1];
        for (; k + 8 <= end; k += 8) {
            int s0 = esrc[k + 0], s1 = esrc[k + 1], s2 = esrc[k + 2], s3 = esrc[k + 3];
            int s4 = esrc[k + 4], s5 = esrc[k + 5], s6 = esrc[k + 6], s7 = esrc[k + 7];
            a0 += __half2float(h_in[(size_t)s0 * D + lane]);
            a1 += __half2float(h_in[(size_t)s1 * D + lane]);
            a2 += __half2float(h_in[(size_t)s2 * D + lane]);
            a3 += __half2float(h_in[(size_t)s3 * D + lane]);
            a4 += __half2float(h_in[(size_t)s4 * D + lane]);
            a5 += __half2float(h_in[(size_t)s5 * D + lane]);
            a6 += __half2float(h_in[(size_t)s6 * D + lane]);
            a7 += __half2float(h_in[(size_t)s7 * D + lane]);
        }
        if (k + 4 <= end) {
            int s0 = esrc[k + 0], s1 = esrc[k + 1], s2 = esrc[k + 2], s3 = esrc[k + 3];
            a1 += __half2float(h_in[(size_t)s0 * D + lane]);
            a2 += __half2float(h_in[(size_t)s1 * D + lane]);
            a3 += __half2float(h_in[(size_t)s2 * D + lane]);
            a4 += __half2float(h_in[(size_t)s3 * D + lane]);
            k += 4;
        }
        if (k + 2 <= end) {
            int s0 = esrc[k + 0], s1 = esrc[k + 1];
            a5 += __half2float(h_in[(size_t)s0 * D + lane]);
            a6 += __half2float(h_in[(size_t)s1 * D + lane]);
            k += 2;
        }
        if (k < end)
            a7 += __half2float(h_in[(size_t)esrc[k] * D + lane]);

        vs[w][lane] = ((a0 + a1) + (a2 + a3)) + ((a4 + a5) + (a6 + a7));
        // wave-local LDS RAW: no barrier needed
        float o = 0.f;
#pragma unroll
        for (int i = 0; i < D; ++i)
            o = fmaf(vs[w][i], Ws[i][lane], o);
        h_out[(size_t)n * D + lane] = __float2half(fmaxf(o, 0.f));
    }
}

// ===== Layer 3 fused with L2-normalize + 64->16 output linear =============
__global__ __launch_bounds__(256) void gin_final_kernel(
        const __half* __restrict__ h_in,
        const int* __restrict__ ofs,
        const int* __restrict__ esrc,
        const float* __restrict__ W,
        const float* __restrict__ W_out,
        const float* __restrict__ b_out,
        float* __restrict__ out,    // [N,16]
        float* __restrict__ feat) { // [N,64]
    __shared__ float Ws[D][D];          // 16KB
    __shared__ float Wo[D][N_CLASSES];  // 4KB
    __shared__ float vs[4][D];
    __shared__ float fs[4][D];
    int tid = threadIdx.x;
    for (int k = tid; k < D * D; k += 256)
        Ws[k >> 6][k & 63] = W[k];
    for (int k = tid; k < D * N_CLASSES; k += 256)
        Wo[k >> 4][k & 15] = W_out[k];
    __syncthreads();
    int w = tid >> 6, lane = tid & 63;
    float bias = b_out[lane & 15];

    for (int g = blockIdx.x; g < NGROUPS; g += GIN3_GRID) {
        int n = g * 4 + w;
        float a0 = __half2float(h_in[(size_t)n * D + lane]);
        float a1 = 0.f, a2 = 0.f, a3 = 0.f, a4 = 0.f, a5 = 0.f, a6 = 0.f, a7 = 0.f;
        int k = ofs[n], end = ofs[n + 1];
        for (; k + 8 <= end; k += 8) {
            int s0 = esrc[k + 0], s1 = esrc[k + 1], s2 = esrc[k + 2], s3 = esrc[k + 3];
            int s4 = esrc[k + 4], s5 = esrc[k + 5], s6 = esrc[k + 6], s7 = esrc[k + 7];
            a0 += __half2float(h_in[(size_t)s0 * D + lane]);
            a1 += __half2float(h_in[(size_t)s1 * D + lane]);
            a2 += __half2float(h_in[(size_t)s2 * D + lane]);
            a3 += __half2float(h_in[(size_t)s3 * D + lane]);
            a4 += __half2float(h_in[(size_t)s4 * D + lane]);
            a5 += __half2float(h_in[(size_t)s5 * D + lane]);
            a6 += __half2float(h_in[(size_t)s6 * D + lane]);
            a7 += __half2float(h_in[(size_t)s7 * D + lane]);
        }
        if (k + 4 <= end) {
            int s0 = esrc[k + 0], s1 = esrc[k + 1], s2 = esrc[k + 2], s3 = esrc[k + 3];
            a1 += __half2float(h_in[(size_t)s0 * D + lane]);
            a2 += __half2float(h_in[(size_t)s1 * D + lane]);
            a3 += __half2float(h_in[(size_t)s2 * D + lane]);
            a4 += __half2float(h_in[(size_t)s3 * D + lane]);
            k += 4;
        }
        if (k + 2 <= end) {
            int s0 = esrc[k + 0], s1 = esrc[k + 1];
            a5 += __half2float(h_in[(size_t)s0 * D + lane]);
            a6 += __half2float(h_in[(size_t)s1 * D + lane]);
            k += 2;
        }
        if (k < end)
            a7 += __half2float(h_in[(size_t)esrc[k] * D + lane]);

        vs[w][lane] = ((a0 + a1) + (a2 + a3)) + ((a4 + a5) + (a6 + a7));
        float o = 0.f;
#pragma unroll
        for (int i = 0; i < D; ++i)
            o = fmaf(vs[w][i], Ws[i][lane], o);
        o = fmaxf(o, 0.f);               // h3[lane]

        // L2 normalize across the wave
        float ss = o * o;
#pragma unroll
        for (int off = 32; off; off >>= 1)
            ss += __shfl_xor(ss, off);
        float f = o / fmaxf(sqrtf(ss), 1e-12f);
        feat[(size_t)n * D + lane] = f;
        fs[w][lane] = f;
        // wave-local LDS RAW: no barrier
        if (lane < N_CLASSES) {
            float acc = bias;
#pragma unroll
            for (int i = 0; i < D; ++i)
                acc = fmaf(fs[w][i], Wo[i][lane], acc);
            out[(size_t)n * N_CLASSES + lane] = acc;
        }
    }
}

// ==========================================================================
extern "C" void kernel_launch(void* const* d_in, const int* in_sizes, int n_in,
                              void* d_out, int out_size, void* d_ws, size_t ws_size,
                              hipStream_t stream) {
    const float* x     = (const float*)d_in[0];
    const int*   src   = (const int*)d_in[1];
    const int*   dst   = (const int*)d_in[2];
    const float* W0    = (const float*)d_in[3];
    const float* W1    = (const float*)d_in[4];
    const float* W2    = (const float*)d_in[5];
    const float* W_out = (const float*)d_in[6];
    const float* b_out = (const float*)d_in[7];

    float* out  = (float*)d_out;                                  // [N,16]
    float* feat = (float*)d_out + (size_t)N_NODES * N_CLASSES;    // [N,64]

    const int NB_NODE  = (N_NODES + 255) / 256;       // 391
    const int NB_EDGE4 = (N_EDGES / 4 + 255) / 256;   // 1172
    const int NB_CVT   = (N_NODES * D / 4 + 255) / 256;

    // ws layout (256B-aligned slabs)
    size_t off = 0;
    auto alloc = [&](size_t bytes) { size_t o = off; off = (off + bytes + 255) & ~(size_t)255; return o; };
    size_t o_cnt     = alloc((size_t)N_NODES * 4);
    size_t o_partial = alloc(512 * 4);
    size_t o_ofs     = alloc(((size_t)N_NODES + 1) * 4);
    size_t o_esrc    = alloc((size_t)N_EDGES * 4);
    size_t o_x16     = alloc((size_t)N_NODES * D * 2);
    size_t o_bufA    = alloc((size_t)N_NODES * D * 2);
    size_t o_bufB    = alloc((size_t)N_NODES * D * 2);

    char* w8 = (char*)d_ws;
    int*    cnt     = (int*)(w8 + o_cnt);
    int*    partial = (int*)(w8 + o_partial);
    int*    ofs     = (int*)(w8 + o_ofs);
    int*    esrc    = (int*)(w8 + o_esrc);
    __half* x16     = (__half*)(w8 + o_x16);
    __half* bufA    = (__half*)(w8 + o_bufA);
    __half* bufB    = (__half*)(w8 + o_bufB);

    // --- CSR build (once, reused by 3 layers) ---
    hipMemsetAsync(cnt, 0, (size_t)N_NODES * 4, stream);
    hist_kernel<<<NB_EDGE4, 256, 0, stream>>>(dst, cnt);
    scan_block_kernel<<<NB_NODE, 256, 0, stream>>>(cnt, ofs, partial);
    scan_partials_kernel<<<1, 512, 0, stream>>>(partial, NB_NODE);
    scan_add_kernel<<<NB_NODE, 256, 0, stream>>>(ofs, partial);
    scatter_edges_kernel<<<2048, 256, 0, stream>>>(src, dst, ofs, cnt, esrc);

    // --- x -> fp16 (overlappable with CSR build in the graph) ---
    cvt_f32_f16_kernel<<<NB_CVT, 256, 0, stream>>>(x, x16);

    // --- 3 fused GIN layers; layer 3 fused with normalize + output head ---
    gin_layer_kernel<<<GIN_GRID, 256, 0, stream>>>(x16,  ofs, esrc, W0, bufA);
    gin_layer_kernel<<<GIN_GRID, 256, 0, stream>>>(bufA, ofs, esrc, W1, bufB);
    gin_final_kernel<<<GIN3_GRID, 256, 0, stream>>>(bufB, ofs, esrc, W2, W_out, b_out, out, feat);
}

// Round 5
// 362.262 us; speedup vs baseline: 2.8158x; 1.0266x over previous
//
#include <hip/hip_runtime.h>
#include <hip/hip_fp16.h>

#define N_NODES 100000
#define N_EDGES 1200000
#define D 64
#define N_CLASSES 16
#define NG8 (N_NODES / 8)          // 12500 groups of 8 nodes (divisible)
#define GIN_GRID 2048              // 8 blocks/CU (LDS 18KB -> 8 max)
#define NXCD 8
#define DRANGE ((N_NODES + NXCD - 1) / NXCD)   // 12500

// ======================= CSR build kernels ================================

__global__ void hist_kernel(const int* __restrict__ dst, int* __restrict__ cnt) {
    int e = (blockIdx.x * 256 + threadIdx.x) * 4;
    if (e + 4 <= N_EDGES) {
        int4 d4 = *(const int4*)(dst + e);
        atomicAdd(&cnt[d4.x], 1); atomicAdd(&cnt[d4.y], 1);
        atomicAdd(&cnt[d4.z], 1); atomicAdd(&cnt[d4.w], 1);
    } else {
        for (int k = e; k < N_EDGES; ++k) atomicAdd(&cnt[dst[k]], 1);
    }
}

__global__ void scan_block_kernel(const int* __restrict__ cnt,
                                  int* __restrict__ ofs,
                                  int* __restrict__ partial) {
    __shared__ int s[256];
    int tid = threadIdx.x;
    int i = blockIdx.x * 256 + tid;
    int v = (i < N_NODES) ? cnt[i] : 0;
    s[tid] = v;
    __syncthreads();
    for (int d = 1; d < 256; d <<= 1) {
        int t = (tid >= d) ? s[tid - d] : 0;
        __syncthreads();
        s[tid] += t;
        __syncthreads();
    }
    if (i < N_NODES) ofs[i] = s[tid] - v;
    if (tid == 255) partial[blockIdx.x] = s[255];
}

__global__ void scan_partials_kernel(int* __restrict__ partial, int nb) {
    __shared__ int s[512];
    int tid = threadIdx.x;
    int v = (tid < nb) ? partial[tid] : 0;
    s[tid] = v;
    __syncthreads();
    for (int d = 1; d < 512; d <<= 1) {
        int t = (tid >= d) ? s[tid - d] : 0;
        __syncthreads();
        s[tid] += t;
        __syncthreads();
    }
    if (tid < nb) partial[tid] = s[tid] - v;
}

__global__ void scan_add_kernel(int* __restrict__ ofs, const int* __restrict__ partial) {
    int i = blockIdx.x * 256 + threadIdx.x;
    if (i < N_NODES) ofs[i] += partial[blockIdx.x];
    if (i == 0) ofs[N_NODES] = N_EDGES;
}

// XCD-range-partitioned scatter (round-4): each XCD writes only its own
// 12500-node dst range -> private-L2-resident esrc slice.
__global__ __launch_bounds__(256) void scatter_edges_kernel(
        const int* __restrict__ src,
        const int* __restrict__ dst,
        const int* __restrict__ ofs,
        int* __restrict__ cnt,
        int* __restrict__ esrc) {
    int g = blockIdx.x & (NXCD - 1);
    int lo = g * DRANGE, hi = lo + DRANGE;
    int t = (blockIdx.x >> 3) * 256 + threadIdx.x;
    const int NCH = N_EDGES / 4;
    const int STRIDE = (2048 / NXCD) * 256;
    for (int c = t; c < NCH; c += STRIDE) {
        int4 s4 = ((const int4*)src)[c];
        int4 d4 = ((const int4*)dst)[c];
        if (d4.x >= lo && d4.x < hi) esrc[ofs[d4.x] + atomicSub(&cnt[d4.x], 1) - 1] = s4.x;
        if (d4.y >= lo && d4.y < hi) esrc[ofs[d4.y] + atomicSub(&cnt[d4.y], 1) - 1] = s4.y;
        if (d4.z >= lo && d4.z < hi) esrc[ofs[d4.z] + atomicSub(&cnt[d4.z], 1) - 1] = s4.z;
        if (d4.w >= lo && d4.w < hi) esrc[ofs[d4.w] + atomicSub(&cnt[d4.w], 1) - 1] = s4.w;
    }
}

// ================= f32 -> f16 convert (for layer-0 input) =================
__global__ void cvt_f32_f16_kernel(const float* __restrict__ in, __half* __restrict__ out) {
    const int N4 = N_NODES * D / 4;
    int i = blockIdx.x * 256 + threadIdx.x;
    if (i < N4) {
        float4 v = ((const float4*)in)[i];
        ((__half2*)out)[2 * i + 0] = __floats2half2_rn(v.x, v.y);
        ((__half2*)out)[2 * i + 1] = __floats2half2_rn(v.z, v.w);
    }
}

// ============ Fused GIN layer: gather-sum + MLP + relu (fp16 h) ===========
// 2 nodes per wave: half-wave (32 lanes) per node, each lane owns 2 adjacent
// channels via __half2. Halves VMEM instructions/edge and doubles
// edges-in-flight per wave vs the 1-node-per-wave layout.
__global__ __launch_bounds__(256) void gin_layer_kernel(
        const __half* __restrict__ h_in,
        const int* __restrict__ ofs,
        const int* __restrict__ esrc,
        const float* __restrict__ W,
        __half* __restrict__ h_out) {
    __shared__ float Ws[D][D];       // [in][out], 16KB
    __shared__ float vs[4][2][D];    // per-wave, per-half node row, 2KB
    int tid = threadIdx.x;
    for (int k = tid; k < D * D; k += 256)
        Ws[k >> 6][k & 63] = W[k];
    __syncthreads();   // the only barrier
    int w = tid >> 6;
    int lane = tid & 63;
    int hh = lane >> 5;        // which node of the pair
    int c2 = lane & 31;        // half2 channel index (channels 2c2, 2c2+1)
    const __half2* hp = (const __half2*)h_in;

#define GATH(A, S) { float2 q = __half22float2(hp[(S) * 32 + c2]); A.x += q.x; A.y += q.y; }

    for (int g = blockIdx.x; g < NG8; g += GIN_GRID) {
        int n = g * 8 + w * 2 + hh;
        float2 a0 = __half22float2(hp[n * 32 + c2]);   // self term
        float2 a1 = {0.f, 0.f}, a2 = {0.f, 0.f}, a3 = {0.f, 0.f};
        float2 a4 = {0.f, 0.f}, a5 = {0.f, 0.f}, a6 = {0.f, 0.f}, a7 = {0.f, 0.f};
        int k = ofs[n], end = ofs[n + 1];
        for (; k + 8 <= end; k += 8) {
            int s0 = esrc[k + 0], s1 = esrc[k + 1], s2 = esrc[k + 2], s3 = esrc[k + 3];
            int s4 = esrc[k + 4], s5 = esrc[k + 5], s6 = esrc[k + 6], s7 = esrc[k + 7];
            GATH(a0, s0) GATH(a1, s1) GATH(a2, s2) GATH(a3, s3)
            GATH(a4, s4) GATH(a5, s5) GATH(a6, s6) GATH(a7, s7)
        }
        if (k + 4 <= end) {
            int s0 = esrc[k + 0], s1 = esrc[k + 1], s2 = esrc[k + 2], s3 = esrc[k + 3];
            GATH(a1, s0) GATH(a2, s1) GATH(a3, s2) GATH(a4, s3)
            k += 4;
        }
        if (k + 2 <= end) {
            int s0 = esrc[k + 0], s1 = esrc[k + 1];
            GATH(a5, s0) GATH(a6, s1)
            k += 2;
        }
        if (k < end)
            GATH(a7, esrc[k])

        float sx = ((a0.x + a1.x) + (a2.x + a3.x)) + ((a4.x + a5.x) + (a6.x + a7.x));
        float sy = ((a0.y + a1.y) + (a2.y + a3.y)) + ((a4.y + a5.y) + (a6.y + a7.y));
        vs[w][hh][2 * c2 + 0] = sx;
        vs[w][hh][2 * c2 + 1] = sy;
        // wave-local LDS RAW: no barrier needed (lgkmcnt orders it)
        float o0 = 0.f, o1 = 0.f;
#pragma unroll
        for (int i = 0; i < D; ++i) {
            float vi = vs[w][hh][i];
            o0 = fmaf(vi, Ws[i][2 * c2 + 0], o0);
            o1 = fmaf(vi, Ws[i][2 * c2 + 1], o1);
        }
        ((__half2*)h_out)[n * 32 + c2] = __floats2half2_rn(fmaxf(o0, 0.f), fmaxf(o1, 0.f));
    }
}

// ============ Final: L2-normalize + 64->16 linear (fp16 in) ===============
__global__ __launch_bounds__(256) void final_kernel(
        const __half* __restrict__ h,
        const float* __restrict__ W_out,
        const float* __restrict__ b_out,
        float* __restrict__ out,    // [N,16]
        float* __restrict__ feat) { // [N,64]
    __shared__ float Wo[D][N_CLASSES];  // 4KB
    __shared__ float fs[4][2][D];       // 2KB
    int tid = threadIdx.x;
    for (int k = tid; k < D * N_CLASSES; k += 256)
        Wo[k >> 4][k & 15] = W_out[k];
    __syncthreads();
    int w = tid >> 6;
    int lane = tid & 63;
    int hh = lane >> 5;
    int c2 = lane & 31;
    const __half2* hp = (const __half2*)h;
    float bias = b_out[lane & 15];

    for (int g = blockIdx.x; g < NG8; g += GIN_GRID) {
        int n = g * 8 + w * 2 + hh;
        float2 v = __half22float2(hp[n * 32 + c2]);
        float ss = v.x * v.x + v.y * v.y;
#pragma unroll
        for (int off = 16; off; off >>= 1)          // stays within half-wave
            ss += __shfl_xor(ss, off);
        float rinv = 1.f / fmaxf(sqrtf(ss), 1e-12f);
        float f0 = v.x * rinv, f1 = v.y * rinv;
        ((float2*)feat)[n * 32 + c2] = make_float2(f0, f1);
        fs[w][hh][2 * c2 + 0] = f0;
        fs[w][hh][2 * c2 + 1] = f1;
        // wave-local LDS RAW: no barrier
        if (c2 < N_CLASSES) {
            float acc = bias;
#pragma unroll
            for (int i = 0; i < D; ++i)
                acc = fmaf(fs[w][hh][i], Wo[i][c2], acc);
            out[n * N_CLASSES + c2] = acc;
        }
    }
}

// ==========================================================================
extern "C" void kernel_launch(void* const* d_in, const int* in_sizes, int n_in,
                              void* d_out, int out_size, void* d_ws, size_t ws_size,
                              hipStream_t stream) {
    const float* x     = (const float*)d_in[0];
    const int*   src   = (const int*)d_in[1];
    const int*   dst   = (const int*)d_in[2];
    const float* W0    = (const float*)d_in[3];
    const float* W1    = (const float*)d_in[4];
    const float* W2    = (const float*)d_in[5];
    const float* W_out = (const float*)d_in[6];
    const float* b_out = (const float*)d_in[7];

    float* out  = (float*)d_out;                                  // [N,16]
    float* feat = (float*)d_out + (size_t)N_NODES * N_CLASSES;    // [N,64]

    const int NB_NODE  = (N_NODES + 255) / 256;       // 391
    const int NB_EDGE4 = (N_EDGES / 4 + 255) / 256;   // 1172
    const int NB_CVT   = (N_NODES * D / 4 + 255) / 256;

    // ws layout (256B-aligned slabs)
    size_t off = 0;
    auto alloc = [&](size_t bytes) { size_t o = off; off = (off + bytes + 255) & ~(size_t)255; return o; };
    size_t o_cnt     = alloc((size_t)N_NODES * 4);
    size_t o_partial = alloc(512 * 4);
    size_t o_ofs     = alloc(((size_t)N_NODES + 1) * 4);
    size_t o_esrc    = alloc((size_t)N_EDGES * 4);
    size_t o_x16     = alloc((size_t)N_NODES * D * 2);
    size_t o_bufA    = alloc((size_t)N_NODES * D * 2);
    size_t o_bufB    = alloc((size_t)N_NODES * D * 2);

    char* w8 = (char*)d_ws;
    int*    cnt     = (int*)(w8 + o_cnt);
    int*    partial = (int*)(w8 + o_partial);
    int*    ofs     = (int*)(w8 + o_ofs);
    int*    esrc    = (int*)(w8 + o_esrc);
    __half* x16     = (__half*)(w8 + o_x16);
    __half* bufA    = (__half*)(w8 + o_bufA);
    __half* bufB    = (__half*)(w8 + o_bufB);

    // --- CSR build (once, reused by 3 layers) ---
    hipMemsetAsync(cnt, 0, (size_t)N_NODES * 4, stream);
    hist_kernel<<<NB_EDGE4, 256, 0, stream>>>(dst, cnt);
    scan_block_kernel<<<NB_NODE, 256, 0, stream>>>(cnt, ofs, partial);
    scan_partials_kernel<<<1, 512, 0, stream>>>(partial, NB_NODE);
    scan_add_kernel<<<NB_NODE, 256, 0, stream>>>(ofs, partial);
    scatter_edges_kernel<<<2048, 256, 0, stream>>>(src, dst, ofs, cnt, esrc);

    // --- x -> fp16 ---
    cvt_f32_f16_kernel<<<NB_CVT, 256, 0, stream>>>(x, x16);

    // --- 3 fused GIN layers (all identical structure), then final ---
    gin_layer_kernel<<<GIN_GRID, 256, 0, stream>>>(x16,  ofs, esrc, W0, bufA);
    gin_layer_kernel<<<GIN_GRID, 256, 0, stream>>>(bufA, ofs, esrc, W1, bufB);
    gin_layer_kernel<<<GIN_GRID, 256, 0, stream>>>(bufB, ofs, esrc, W2, bufA);
    final_kernel<<<GIN_GRID, 256, 0, stream>>>(bufA, W_out, b_out, out, feat);
}

// Round 6
// 327.599 us; speedup vs baseline: 3.1138x; 1.1058x over previous
//
#include <hip/hip_runtime.h>
#include <hip/hip_fp16.h>

#define N_NODES 100000
#define N_EDGES 1200000
#define D 64
#define N_CLASSES 16
#define NG8  (N_NODES / 8)         // half-wave groups (final kernel)
#define NG16 (N_NODES / 16)        // quarter-wave groups (gin layers), 6250
#define GIN_GRID 2048
#define NXCD 8
#define DRANGE ((N_NODES + NXCD - 1) / NXCD)   // 12500

// ======================= CSR build kernels ================================

__global__ void hist_kernel(const int* __restrict__ dst, int* __restrict__ cnt) {
    int e = (blockIdx.x * 256 + threadIdx.x) * 4;
    if (e + 4 <= N_EDGES) {
        int4 d4 = *(const int4*)(dst + e);
        atomicAdd(&cnt[d4.x], 1); atomicAdd(&cnt[d4.y], 1);
        atomicAdd(&cnt[d4.z], 1); atomicAdd(&cnt[d4.w], 1);
    } else {
        for (int k = e; k < N_EDGES; ++k) atomicAdd(&cnt[dst[k]], 1);
    }
}

__global__ void scan_block_kernel(const int* __restrict__ cnt,
                                  int* __restrict__ ofs,
                                  int* __restrict__ partial) {
    __shared__ int s[256];
    int tid = threadIdx.x;
    int i = blockIdx.x * 256 + tid;
    int v = (i < N_NODES) ? cnt[i] : 0;
    s[tid] = v;
    __syncthreads();
    for (int d = 1; d < 256; d <<= 1) {
        int t = (tid >= d) ? s[tid - d] : 0;
        __syncthreads();
        s[tid] += t;
        __syncthreads();
    }
    if (i < N_NODES) ofs[i] = s[tid] - v;
    if (tid == 255) partial[blockIdx.x] = s[255];
}

__global__ void scan_partials_kernel(int* __restrict__ partial, int nb) {
    __shared__ int s[512];
    int tid = threadIdx.x;
    int v = (tid < nb) ? partial[tid] : 0;
    s[tid] = v;
    __syncthreads();
    for (int d = 1; d < 512; d <<= 1) {
        int t = (tid >= d) ? s[tid - d] : 0;
        __syncthreads();
        s[tid] += t;
        __syncthreads();
    }
    if (tid < nb) partial[tid] = s[tid] - v;
}

__global__ void scan_add_kernel(int* __restrict__ ofs, const int* __restrict__ partial) {
    int i = blockIdx.x * 256 + threadIdx.x;
    if (i < N_NODES) ofs[i] += partial[blockIdx.x];
    if (i == 0) ofs[N_NODES] = N_EDGES;
}

// XCD-range-partitioned scatter: each XCD writes only its own dst range ->
// private-L2-resident esrc slice (kills cross-XCD write amplification).
__global__ __launch_bounds__(256) void scatter_edges_kernel(
        const int* __restrict__ src,
        const int* __restrict__ dst,
        const int* __restrict__ ofs,
        int* __restrict__ cnt,
        int* __restrict__ esrc) {
    int g = blockIdx.x & (NXCD - 1);
    int lo = g * DRANGE, hi = lo + DRANGE;
    int t = (blockIdx.x >> 3) * 256 + threadIdx.x;
    const int NCH = N_EDGES / 4;
    const int STRIDE = (2048 / NXCD) * 256;
    for (int c = t; c < NCH; c += STRIDE) {
        int4 s4 = ((const int4*)src)[c];
        int4 d4 = ((const int4*)dst)[c];
        if (d4.x >= lo && d4.x < hi) esrc[ofs[d4.x] + atomicSub(&cnt[d4.x], 1) - 1] = s4.x;
        if (d4.y >= lo && d4.y < hi) esrc[ofs[d4.y] + atomicSub(&cnt[d4.y], 1) - 1] = s4.y;
        if (d4.z >= lo && d4.z < hi) esrc[ofs[d4.z] + atomicSub(&cnt[d4.z], 1) - 1] = s4.z;
        if (d4.w >= lo && d4.w < hi) esrc[ofs[d4.w] + atomicSub(&cnt[d4.w], 1) - 1] = s4.w;
    }
}

// ================= f32 -> f16 convert (layer-0 input) =====================
__global__ void cvt_f32_f16_kernel(const float* __restrict__ in, __half* __restrict__ out) {
    const int N4 = N_NODES * D / 4;
    int i = blockIdx.x * 256 + threadIdx.x;
    if (i < N4) {
        float4 v = ((const float4*)in)[i];
        ((__half2*)out)[2 * i + 0] = __floats2half2_rn(v.x, v.y);
        ((__half2*)out)[2 * i + 1] = __floats2half2_rn(v.z, v.w);
    }
}

// ============ Fused GIN layer: gather-sum + MLP + relu (fp16 h) ===========
// Quarter-wave layout: 16 lanes per node, each lane owns 4 channels (uint2 =
// 2x half2 = 8B). One gather instruction fetches 4 edges' rows -> 0.25 VMEM
// instr/edge. Inner loop issues 8 predicated gathers (32 edges in flight per
// wave), tail folded into the same predicated pack via index clamping.
__global__ __launch_bounds__(256) void gin_layer_kernel(
        const __half* __restrict__ h_in,
        const int* __restrict__ ofs,
        const int* __restrict__ esrc,
        const float* __restrict__ W,
        __half* __restrict__ h_out) {
    __shared__ float Ws[D][D];                       // [in][out], 16KB
    __shared__ __align__(16) float vs[4][4][68];     // +4 pad: quarters hit distinct banks
    int tid = threadIdx.x;
    for (int k = tid; k < D * D; k += 256)
        Ws[k >> 6][k & 63] = W[k];
    __syncthreads();   // the only barrier
    int w = tid >> 6;
    int lane = tid & 63;
    int q = lane >> 4;         // node within group of 4
    int c4 = lane & 15;        // uint2 slot: channels 4*c4 .. 4*c4+3
    const uint2* hp = (const uint2*)h_in;  // row = 16 uint2

    for (int g = blockIdx.x; g < NG16; g += GIN_GRID) {
        int n = g * 16 + w * 4 + q;
        uint2 self = hp[n * 16 + c4];
        float2 sl = __half22float2(*(const __half2*)&self.x);
        float2 sh = __half22float2(*(const __half2*)&self.y);
        float a0 = sl.x, a1 = sl.y, a2 = sh.x, a3 = sh.y;

        int k = ofs[n], end = ofs[n + 1];
        while (k < end) {
            int sIdx[8];
            uint2 qv[8];
#pragma unroll
            for (int j = 0; j < 8; ++j) {
                int kk = k + j;
                sIdx[j] = esrc[(kk < end) ? kk : (end - 1)];  // clamped: always valid
            }
#pragma unroll
            for (int j = 0; j < 8; ++j) {
                uint2 r = hp[sIdx[j] * 16 + c4];
                qv[j].x = (k + j < end) ? r.x : 0u;  // zero bits == zero halfs
                qv[j].y = (k + j < end) ? r.y : 0u;
            }
#pragma unroll
            for (int j = 0; j < 8; ++j) {
                float2 lo = __half22float2(*(const __half2*)&qv[j].x);
                float2 hi = __half22float2(*(const __half2*)&qv[j].y);
                a0 += lo.x; a1 += lo.y; a2 += hi.x; a3 += hi.y;
            }
            k += 8;
        }

        *(float4*)&vs[w][q][4 * c4] = make_float4(a0, a1, a2, a3);
        // wave-local LDS RAW: ordered by lgkmcnt, no barrier
        float o0 = 0.f, o1 = 0.f, o2 = 0.f, o3 = 0.f;
#pragma unroll
        for (int i = 0; i < D; ++i) {
            float vi = vs[w][q][i];                       // broadcast within quarter
            float4 wr = *(const float4*)&Ws[i][4 * c4];   // 2 lanes/bank: free
            o0 = fmaf(vi, wr.x, o0); o1 = fmaf(vi, wr.y, o1);
            o2 = fmaf(vi, wr.z, o2); o3 = fmaf(vi, wr.w, o3);
        }
        uint2 ov;
        *(__half2*)&ov.x = __floats2half2_rn(fmaxf(o0, 0.f), fmaxf(o1, 0.f));
        *(__half2*)&ov.y = __floats2half2_rn(fmaxf(o2, 0.f), fmaxf(o3, 0.f));
        ((uint2*)h_out)[n * 16 + c4] = ov;
    }
}

// ============ Final: L2-normalize + 64->16 linear (fp16 in) ===============
__global__ __launch_bounds__(256) void final_kernel(
        const __half* __restrict__ h,
        const float* __restrict__ W_out,
        const float* __restrict__ b_out,
        float* __restrict__ out,    // [N,16]
        float* __restrict__ feat) { // [N,64]
    __shared__ float Wo[D][N_CLASSES];
    __shared__ float fs[4][2][D];
    int tid = threadIdx.x;
    for (int k = tid; k < D * N_CLASSES; k += 256)
        Wo[k >> 4][k & 15] = W_out[k];
    __syncthreads();
    int w = tid >> 6;
    int lane = tid & 63;
    int hh = lane >> 5;
    int c2 = lane & 31;
    const __half2* hp = (const __half2*)h;
    float bias = b_out[lane & 15];

    for (int g = blockIdx.x; g < NG8; g += GIN_GRID) {
        int n = g * 8 + w * 2 + hh;
        float2 v = __half22float2(hp[n * 32 + c2]);
        float ss = v.x * v.x + v.y * v.y;
#pragma unroll
        for (int off = 16; off; off >>= 1)   // stays within half-wave
            ss += __shfl_xor(ss, off);
        float rinv = 1.f / fmaxf(sqrtf(ss), 1e-12f);
        float f0 = v.x * rinv, f1 = v.y * rinv;
        ((float2*)feat)[n * 32 + c2] = make_float2(f0, f1);
        fs[w][hh][2 * c2 + 0] = f0;
        fs[w][hh][2 * c2 + 1] = f1;
        // wave-local LDS RAW: no barrier
        if (c2 < N_CLASSES) {
            float acc = bias;
#pragma unroll
            for (int i = 0; i < D; ++i)
                acc = fmaf(fs[w][hh][i], Wo[i][c2], acc);
            out[n * N_CLASSES + c2] = acc;
        }
    }
}

// ==========================================================================
extern "C" void kernel_launch(void* const* d_in, const int* in_sizes, int n_in,
                              void* d_out, int out_size, void* d_ws, size_t ws_size,
                              hipStream_t stream) {
    const float* x     = (const float*)d_in[0];
    const int*   src   = (const int*)d_in[1];
    const int*   dst   = (const int*)d_in[2];
    const float* W0    = (const float*)d_in[3];
    const float* W1    = (const float*)d_in[4];
    const float* W2    = (const float*)d_in[5];
    const float* W_out = (const float*)d_in[6];
    const float* b_out = (const float*)d_in[7];

    float* out  = (float*)d_out;                                  // [N,16]
    float* feat = (float*)d_out + (size_t)N_NODES * N_CLASSES;    // [N,64]

    const int NB_NODE  = (N_NODES + 255) / 256;       // 391
    const int NB_EDGE4 = (N_EDGES / 4 + 255) / 256;   // 1172
    const int NB_CVT   = (N_NODES * D / 4 + 255) / 256;

    // ws layout (256B-aligned slabs)
    size_t off = 0;
    auto alloc = [&](size_t bytes) { size_t o = off; off = (off + bytes + 255) & ~(size_t)255; return o; };
    size_t o_cnt     = alloc((size_t)N_NODES * 4);
    size_t o_partial = alloc(512 * 4);
    size_t o_ofs     = alloc(((size_t)N_NODES + 1) * 4);
    size_t o_esrc    = alloc((size_t)N_EDGES * 4);
    size_t o_x16     = alloc((size_t)N_NODES * D * 2);
    size_t o_bufA    = alloc((size_t)N_NODES * D * 2);
    size_t o_bufB    = alloc((size_t)N_NODES * D * 2);

    char* w8 = (char*)d_ws;
    int*    cnt     = (int*)(w8 + o_cnt);
    int*    partial = (int*)(w8 + o_partial);
    int*    ofs     = (int*)(w8 + o_ofs);
    int*    esrc    = (int*)(w8 + o_esrc);
    __half* x16     = (__half*)(w8 + o_x16);
    __half* bufA    = (__half*)(w8 + o_bufA);
    __half* bufB    = (__half*)(w8 + o_bufB);

    // --- CSR build (once, reused by 3 layers) ---
    hipMemsetAsync(cnt, 0, (size_t)N_NODES * 4, stream);
    hist_kernel<<<NB_EDGE4, 256, 0, stream>>>(dst, cnt);
    scan_block_kernel<<<NB_NODE, 256, 0, stream>>>(cnt, ofs, partial);
    scan_partials_kernel<<<1, 512, 0, stream>>>(partial, NB_NODE);
    scan_add_kernel<<<NB_NODE, 256, 0, stream>>>(ofs, partial);
    scatter_edges_kernel<<<2048, 256, 0, stream>>>(src, dst, ofs, cnt, esrc);

    // --- x -> fp16 ---
    cvt_f32_f16_kernel<<<NB_CVT, 256, 0, stream>>>(x, x16);

    // --- 3 fused GIN layers, then final ---
    gin_layer_kernel<<<GIN_GRID, 256, 0, stream>>>(x16,  ofs, esrc, W0, bufA);
    gin_layer_kernel<<<GIN_GRID, 256, 0, stream>>>(bufA, ofs, esrc, W1, bufB);
    gin_layer_kernel<<<GIN_GRID, 256, 0, stream>>>(bufB, ofs, esrc, W2, bufA);
    final_kernel<<<GIN_GRID, 256, 0, stream>>>(bufA, W_out, b_out, out, feat);
}